// Round 9
// baseline (243.426 us; speedup 1.0000x reference)
//
#include <hip/hip_runtime.h>

typedef unsigned short u16;
typedef unsigned int u32;
typedef __attribute__((ext_vector_type(8))) short s16x8;
typedef __attribute__((ext_vector_type(4))) short s16x4;
typedef __attribute__((ext_vector_type(4))) float f32x4;

#define S_LEN 4096
#define D_DIM 1024
#define NH    16
#define HDIM  64
#define KVB   128
#define QB    128

#define AS1 __attribute__((address_space(1)))
#define AS3 __attribute__((address_space(3)))

__device__ __forceinline__ u16 f2bf(float f) {
  unsigned u = __float_as_uint(f);
  u += 0x7FFF + ((u >> 16) & 1);   // RNE
  return (u16)(u >> 16);
}

// packed RNE f32x2 -> bf16x2 in one op
__device__ __forceinline__ u32 cvtpk2(float a, float b) {
  float r;
  asm("v_cvt_pk_bf16_f32 %0, %1, %2" : "=v"(r) : "v"(a), "v"(b));
  return __float_as_uint(r);
}

__device__ __forceinline__ u16 f2bf_pk(float f) {
  return (u16)(cvtpk2(f, f) & 0xffffu);
}

// 2^x in one instruction
__device__ __forceinline__ float exp2fast(float x) {
  float r;
  asm("v_exp_f32 %0, %1" : "=v"(r) : "v"(x));
  return r;
}

// async global->LDS, 16B per lane; LDS dest is wave-uniform (HW adds lane*16)
__device__ __forceinline__ void load_lds16(const void* g, void* l) {
  __builtin_amdgcn_global_load_lds((AS1 void*)g, (AS3 void*)l, 16, 0, 0);
}

__device__ __forceinline__ unsigned lds_addr32(const void* p) {
  return (unsigned)(unsigned long long)(AS3 const char*)p;
}

// hardware transpose read: on a row-major [16][16] bf16 subtile with per-lane
// addr = base + l*8, lane(g,r) receives elements [row=4g+j][col=r], j=0..3
__device__ __forceinline__ s16x4 ds_read_tr16(unsigned addr) {
  s16x4 r;
  asm volatile("ds_read_b64_tr_b16 %0, %1" : "=v"(r) : "v"(addr));
  return r;
}

// ---------------- fp32 -> bf16 (x in 4 slabs + 4 weights, one launch) --------
__global__ __launch_bounds__(256) void cvt_all(const float* __restrict__ x,
                                               const float* __restrict__ w0,
                                               const float* __restrict__ w1,
                                               const float* __restrict__ w2,
                                               const float* __restrict__ w3,
                                               u16* xb, u16* o0, u16* o1,
                                               u16* o2, u16* o3) {
  const float* in; u16* out;
  const int slab = blockIdx.y;
  switch (slab) {
    case 0: case 1: case 2: case 3:
      in = x + (size_t)slab * D_DIM * 1024; out = xb + (size_t)slab * D_DIM * 1024; break;
    case 4: in = w0; out = o0; break;
    case 5: in = w1; out = o1; break;
    case 6: in = w2; out = o2; break;
    default: in = w3; out = o3; break;
  }
  int i = (blockIdx.x * 256 + threadIdx.x) * 4;
  float4 v = *(const float4*)(in + i);
  ushort4 o;
  o.x = f2bf(v.x); o.y = f2bf(v.y); o.z = f2bf(v.z); o.w = f2bf(v.w);
  *(ushort4*)(out + i) = o;
}

// ---------------- GEMM: C[M,N] = cscale * A[M,K] * B[N,K]^T ----------------
// m97 structure: tile 128x128, BK=32, 4 waves (2x2), wave tile 64x64 (4x4 frags),
// 16 MFMA : 8 ds_read_b128 per K-step, double-buffered LDS + prefetch.
struct GemmSmem { u16 As[2][128 * 32]; u16 Bs[2][128 * 32]; };   // 32 KB

template <bool BF16_OUT>
__device__ __forceinline__ void gemm_tile(GemmSmem& sm, const u16* __restrict__ A,
                                          const u16* __restrict__ B,
                                          void* __restrict__ C, int m0, int n0,
                                          int N, int K, float cscale) {
  const int t = threadIdx.x;
  const int l = t & 63, g = l >> 4, r = l & 15;
  const int w = t >> 6, wr = w >> 1, wc = w & 1;
  f32x4 acc[4][4] = {};
  const int swz = (g ^ ((r >> 1) & 3)) << 3;   // read-side granule XOR

  auto stage = [&](int buf, int k0) {
#pragma unroll
    for (int i = 0; i < 2; ++i) {              // A,B: 512 granules of 16B each
      const int gi = i * 256 + t;
      const int row = gi >> 2, cg = gi & 3;
      const int sc = cg ^ ((row >> 1) & 3);
      load_lds16(A + (size_t)(m0 + row) * K + k0 + sc * 8,
                 (char*)sm.As[buf] + (i * 256 + (t & 192)) * 16);
      load_lds16(B + (size_t)(n0 + row) * K + k0 + sc * 8,
                 (char*)sm.Bs[buf] + (i * 256 + (t & 192)) * 16);
    }
  };

  stage(0, 0);
  __syncthreads();
  int cur = 0;
  for (int k0 = 0; k0 < K; k0 += 32) {
    if (k0 + 32 < K) stage(cur ^ 1, k0 + 32);
    s16x8 a[4], b[4];
#pragma unroll
    for (int m = 0; m < 4; ++m)
      a[m] = *(const s16x8*)&sm.As[cur][(wr * 64 + m * 16 + r) * 32 + swz];
#pragma unroll
    for (int n = 0; n < 4; ++n)
      b[n] = *(const s16x8*)&sm.Bs[cur][(wc * 64 + n * 16 + r) * 32 + swz];
#pragma unroll
    for (int m = 0; m < 4; ++m)
#pragma unroll
      for (int n = 0; n < 4; ++n)
        acc[m][n] = __builtin_amdgcn_mfma_f32_16x16x32_bf16(a[m], b[n], acc[m][n], 0, 0, 0);
    __syncthreads();
    cur ^= 1;
  }
  // D layout (verified): col = lane&15, row = 4*(lane>>4) + reg
#pragma unroll
  for (int m = 0; m < 4; ++m)
#pragma unroll
    for (int n = 0; n < 4; ++n)
#pragma unroll
      for (int v = 0; v < 4; ++v) {
        int row = m0 + wr * 64 + m * 16 + g * 4 + v;
        int col = n0 + wc * 64 + n * 16 + r;
        float val = acc[m][n][v] * cscale;
        if (BF16_OUT)
          ((u16*)C)[(size_t)row * N + col] = f2bf_pk(val);
        else
          ((float*)C)[(size_t)row * N + col] = val;
      }
}

// Q is pre-scaled by 0.125*log2(e) so attention works in exp2 domain
#define QSCALE 0.1803368801111204f

__global__ __launch_bounds__(256) void gemm_qkv(const u16* __restrict__ A,
                                                const u16* __restrict__ Bq,
                                                const u16* __restrict__ Bk,
                                                const u16* __restrict__ Bv,
                                                u16* Cq, u16* Ck, u16* Cv_) {
  __shared__ GemmSmem sm;
  // XCD-chunked swizzle: 768 blocks, 96 contiguous tiles per XCD
  const int f = blockIdx.y * 24 + blockIdx.x;
  const int tid = (f & 7) * 96 + (f >> 3);
  const int nby = tid / 24, nbx = tid % 24;
  const int which = nbx >> 3;                  // 8 n-blocks of 128 per matrix
  const u16* B = which == 0 ? Bq : (which == 1 ? Bk : Bv);
  u16* C = which == 0 ? Cq : (which == 1 ? Ck : Cv_);
  const float cs = which == 0 ? QSCALE : 1.0f;
  gemm_tile<true>(sm, A, B, C, nby * 128, (nbx & 7) * 128, D_DIM, D_DIM, cs);
}

__global__ __launch_bounds__(256) void gemm_out(const u16* __restrict__ A,
                                                const u16* __restrict__ B,
                                                float* __restrict__ C) {
  __shared__ GemmSmem sm;
  // XCD-chunked swizzle: 256 blocks, 32 contiguous tiles per XCD
  const int f = blockIdx.y * 8 + blockIdx.x;
  const int tid = (f & 7) * 32 + (f >> 3);
  gemm_tile<false>(sm, A, B, C, (tid >> 3) * 128, (tid & 7) * 128, D_DIM, D_DIM, 1.0f);
}

// ---------------- causal flash attention (swapped, 32 q-rows/wave) -----------
// QBLK=128, 4 waves (256 thr); wave w owns q-rows w*32..w*32+31 as two 16-row
// groups A/B that SHARE every K ds_read and V tr-read (2 MFMAs per load) ->
// per-CU-tile LDS traffic 160KB vs 288KB. Grid 32x16 = 512 blocks = 2/CU for
// cross-phase overlap; big-first qtile mapping for scheduler balance.
__global__ __launch_bounds__(256) void flash_attn(const u16* __restrict__ Q,
                                                  const u16* __restrict__ Kg,
                                                  const u16* __restrict__ V,
                                                  u16* __restrict__ CTX) {
  const int h = blockIdx.y;
  const int hoff = h * HDIM;
  const int t = threadIdx.x, w = t >> 6, l = t & 63, g = l >> 4, r = l & 15;

  __shared__ u16 Kt[2][KVB * 64];    // [kv][hd], granule-XOR swizzled (row&7)
  __shared__ u16 Vt[2][32 * 256];    // 32 subtiles [16kv][16hd] for tr-reads

  auto stage = [&](int buf, int kv0) {
#pragma unroll
    for (int i = 0; i < 4; ++i) {    // 1024 granules each of K and V, 256 thr
      const int gi = i * 256 + t;
      const int krow = gi >> 3, c0 = gi & 7;
      load_lds16(Kg + (size_t)(kv0 + krow) * D_DIM + hoff + ((c0 ^ (krow & 7)) << 3),
                 (char*)Kt[buf] + (i * 256 + (t & 192)) * 16);
      const int sv = gi >> 5, vo = gi & 31;
      load_lds16(V + (size_t)(kv0 + (sv >> 2) * 16 + (vo >> 1)) * D_DIM + hoff +
                     (sv & 3) * 16 + (vo & 1) * 8,
                 (char*)Vt[buf] + (i * 256 + (t & 192)) * 16);
    }
  };

  // big-first qtile mapping: x<16 -> 31-x (32..17 tiles), x>=16 -> x-16 (1..16)
  const int bx = (int)blockIdx.x;
  const int qtile = bx < 16 ? 31 - bx : bx - 16;
  const int q0 = qtile * QB + w * 32;
  const int nt = qtile + 1;

  // Q fragments (B-operand of swapped QK), groups A (rows q0+r) and B (+16)
  const u16* qrowA = Q + (size_t)(q0 + r) * D_DIM + hoff;
  const u16* qrowB = qrowA + 16 * D_DIM;
  const s16x8 aqA0 = *(const s16x8*)(qrowA + g * 8);
  const s16x8 aqA1 = *(const s16x8*)(qrowA + 32 + g * 8);
  const s16x8 aqB0 = *(const s16x8*)(qrowB + g * 8);
  const s16x8 aqB1 = *(const s16x8*)(qrowB + 32 + g * 8);

  f32x4 oA[4] = {}, oB[4] = {};      // O^T: hd = 16hb+4g+reg, q = r (+16 for B)
  float mA = -1e30f, lsA = 0.f, mB = -1e30f, lsB = 0.f;

  stage(0, 0);
  __syncthreads();
  int cur = 0;

  for (int tile = 0; tile < nt; ++tile) {
    if (tile + 1 < nt) stage(cur ^ 1, (tile + 1) * KVB);
    const u16* Kb = Kt[cur];
    const bool lastT = (tile == nt - 1);

    // ---- S^T[128kv x 16q] x2 groups; shared K reads: s*[nb][j], kv=16nb+4g+j
    f32x4 sA[8], sB[8];
    __builtin_amdgcn_s_setprio(1);
#pragma unroll
    for (int nb = 0; nb < 8; ++nb) {
      const int kr = nb * 16 + r;
      const int sw = kr & 7;
      s16x8 bk0 = *(const s16x8*)&Kb[kr * 64 + ((g ^ sw) << 3)];
      s16x8 bk1 = *(const s16x8*)&Kb[kr * 64 + (((4 + g) ^ sw) << 3)];
      f32x4 zA = {0.f, 0.f, 0.f, 0.f}, zB = {0.f, 0.f, 0.f, 0.f};
      zA = __builtin_amdgcn_mfma_f32_16x16x32_bf16(bk0, aqA0, zA, 0, 0, 0);
      zB = __builtin_amdgcn_mfma_f32_16x16x32_bf16(bk0, aqB0, zB, 0, 0, 0);
      zA = __builtin_amdgcn_mfma_f32_16x16x32_bf16(bk1, aqA1, zA, 0, 0, 0);
      zB = __builtin_amdgcn_mfma_f32_16x16x32_bf16(bk1, aqB1, zB, 0, 0, 0);
      sA[nb] = zA; sB[nb] = zB;
    }
    __builtin_amdgcn_s_setprio(0);

    // ---- causal mask (diagonal tile only) ----
    if (lastT) {
      const int qrelA = w * 32 + r;            // q0+r - tile*KVB on diagonal
      const int qrelB = qrelA + 16;
#pragma unroll
      for (int nb = 0; nb < 8; ++nb)
#pragma unroll
        for (int j = 0; j < 4; ++j) {
          const int kvl = 16 * nb + 4 * g + j;
          if (kvl > qrelA) sA[nb][j] = -1e30f;
          if (kvl > qrelB) sB[nb][j] = -1e30f;
        }
    }

    // ---- online softmax per group: in-lane 32, then xor16+xor32 across g ----
    float tmA = -1e30f, tmB = -1e30f;
#pragma unroll
    for (int nb = 0; nb < 8; ++nb) {
      tmA = fmaxf(tmA, fmaxf(fmaxf(sA[nb][0], sA[nb][1]), fmaxf(sA[nb][2], sA[nb][3])));
      tmB = fmaxf(tmB, fmaxf(fmaxf(sB[nb][0], sB[nb][1]), fmaxf(sB[nb][2], sB[nb][3])));
    }
    tmA = fmaxf(tmA, __shfl_xor(tmA, 16, 64));
    tmA = fmaxf(tmA, __shfl_xor(tmA, 32, 64));
    tmB = fmaxf(tmB, __shfl_xor(tmB, 16, 64));
    tmB = fmaxf(tmB, __shfl_xor(tmB, 32, 64));
    const float mnA = fmaxf(mA, tmA), mnB = fmaxf(mB, tmB);
    const float fsA = exp2fast(mA - mnA), fsB = exp2fast(mB - mnB);
    mA = mnA; mB = mnB;
    float psA = 0.f, psB = 0.f;
#pragma unroll
    for (int nb = 0; nb < 8; ++nb)
#pragma unroll
      for (int j = 0; j < 4; ++j) {
        const float pA = exp2fast(sA[nb][j] - mnA);
        const float pB = exp2fast(sB[nb][j] - mnB);
        sA[nb][j] = pA; sB[nb][j] = pB;
        psA += pA; psB += pB;
      }
    psA += __shfl_xor(psA, 16, 64);
    psA += __shfl_xor(psA, 32, 64);
    psB += __shfl_xor(psB, 16, 64);
    psB += __shfl_xor(psB, 32, 64);
    lsA = lsA * fsA + psA;
    lsB = lsB * fsB + psB;
#pragma unroll
    for (int hb = 0; hb < 4; ++hb) {
      oA[hb][0] *= fsA; oA[hb][1] *= fsA; oA[hb][2] *= fsA; oA[hb][3] *= fsA;
      oB[hb][0] *= fsB; oB[hb][1] *= fsB; oB[hb][2] *= fsB; oB[hb][3] *= fsB;
    }

    // ---- pack P^T fragments (k-map both sides: k = 4g+(e&3)+16*(e>>2)) ----
    s16x8 paA[4], paB[4];
#pragma unroll
    for (int ks = 0; ks < 4; ++ks) {
      union { u32 u[4]; s16x8 v; } pk_;
      pk_.u[0] = cvtpk2(sA[2 * ks][0],     sA[2 * ks][1]);
      pk_.u[1] = cvtpk2(sA[2 * ks][2],     sA[2 * ks][3]);
      pk_.u[2] = cvtpk2(sA[2 * ks + 1][0], sA[2 * ks + 1][1]);
      pk_.u[3] = cvtpk2(sA[2 * ks + 1][2], sA[2 * ks + 1][3]);
      paA[ks] = pk_.v;
      pk_.u[0] = cvtpk2(sB[2 * ks][0],     sB[2 * ks][1]);
      pk_.u[1] = cvtpk2(sB[2 * ks][2],     sB[2 * ks][3]);
      pk_.u[2] = cvtpk2(sB[2 * ks + 1][0], sB[2 * ks + 1][1]);
      pk_.u[3] = cvtpk2(sB[2 * ks + 1][2], sB[2 * ks + 1][3]);
      paB[ks] = pk_.v;
    }

    // ---- PV swapped, shared tr-reads: o*[hb] += V^T_frag[ks][hb] · pa*[ks] --
    const unsigned vbase = lds_addr32(Vt[cur]) + (unsigned)(l * 8);
    s16x4 tv[4][4][2];               // [ks][hb][kb]
    auto issue_grp = [&](int ks) {
#pragma unroll
      for (int hb = 0; hb < 4; ++hb) {
        tv[ks][hb][0] = ds_read_tr16(vbase + (unsigned)(((2 * ks) * 4 + hb) * 512));
        tv[ks][hb][1] = ds_read_tr16(vbase + (unsigned)(((2 * ks + 1) * 4 + hb) * 512));
      }
    };
    issue_grp(0);
    issue_grp(1);
#pragma unroll
    for (int ks = 0; ks < 4; ++ks) {
      if (ks < 3) asm volatile("s_waitcnt lgkmcnt(8)" ::: "memory");
      else        asm volatile("s_waitcnt lgkmcnt(0)" ::: "memory");
      __builtin_amdgcn_sched_barrier(0);
      __builtin_amdgcn_s_setprio(1);
#pragma unroll
      for (int hb = 0; hb < 4; ++hb) {
        s16x8 vf = {tv[ks][hb][0][0], tv[ks][hb][0][1], tv[ks][hb][0][2], tv[ks][hb][0][3],
                    tv[ks][hb][1][0], tv[ks][hb][1][1], tv[ks][hb][1][2], tv[ks][hb][1][3]};
        oA[hb] = __builtin_amdgcn_mfma_f32_16x16x32_bf16(vf, paA[ks], oA[hb], 0, 0, 0);
        oB[hb] = __builtin_amdgcn_mfma_f32_16x16x32_bf16(vf, paB[ks], oB[hb], 0, 0, 0);
      }
      __builtin_amdgcn_s_setprio(0);
      if (ks < 2) issue_grp(ks + 2);         // overlap next group with this MFMA
    }
    __syncthreads();                 // prefetch landed; all reads of cur done
    cur ^= 1;
  }

  // ---- normalize + store O^T: lane(g,r): q = q0+r (+16), hd = 16hb+4g+0..3 --
  const float invA = 1.0f / lsA, invB = 1.0f / lsB;
  u16* crowA = CTX + (size_t)(q0 + r) * D_DIM + hoff + 4 * g;
  u16* crowB = crowA + 16 * D_DIM;
#pragma unroll
  for (int hb = 0; hb < 4; ++hb) {
    uint2 pkA, pkB;
    pkA.x = cvtpk2(oA[hb][0] * invA, oA[hb][1] * invA);
    pkA.y = cvtpk2(oA[hb][2] * invA, oA[hb][3] * invA);
    pkB.x = cvtpk2(oB[hb][0] * invB, oB[hb][1] * invB);
    pkB.y = cvtpk2(oB[hb][2] * invB, oB[hb][3] * invB);
    *(uint2*)(crowA + hb * 16) = pkA;
    *(uint2*)(crowB + hb * 16) = pkB;
  }
}

extern "C" void kernel_launch(void* const* d_in, const int* in_sizes, int n_in,
                              void* d_out, int out_size, void* d_ws, size_t ws_size,
                              hipStream_t stream) {
  const float* x  = (const float*)d_in[0];
  const float* Wq = (const float*)d_in[1];
  const float* Wk = (const float*)d_in[2];
  const float* Wv = (const float*)d_in[3];
  const float* Wo = (const float*)d_in[4];

  u16* xb  = (u16*)d_ws;                               // 4096x1024
  u16* Wqb = xb + (size_t)S_LEN * D_DIM;               // 1024x1024 each
  u16* Wkb = Wqb + (size_t)D_DIM * D_DIM;
  u16* Wvb = Wkb + (size_t)D_DIM * D_DIM;
  u16* Wob = Wvb + (size_t)D_DIM * D_DIM;
  u16* Qb  = Wob + (size_t)D_DIM * D_DIM;              // 4096x1024 each
  u16* Kb  = Qb + (size_t)S_LEN * D_DIM;
  u16* Vb  = Kb + (size_t)S_LEN * D_DIM;
  u16* Cb  = Vb + (size_t)S_LEN * D_DIM;

  cvt_all<<<dim3(1024, 8), 256, 0, stream>>>(x, Wq, Wk, Wv, Wo,
                                             xb, Wqb, Wkb, Wvb, Wob);
  gemm_qkv<<<dim3(24, 32), 256, 0, stream>>>(xb, Wqb, Wkb, Wvb, Qb, Kb, Vb);
  flash_attn<<<dim3(32, NH), 256, 0, stream>>>(Qb, Kb, Vb, Cb);
  gemm_out<<<dim3(8, 32), 256, 0, stream>>>(Cb, Wob, (float*)d_out);
}

// Round 10
// 201.500 us; speedup vs baseline: 1.2081x; 1.2081x over previous
//
#include <hip/hip_runtime.h>

typedef unsigned short u16;
typedef unsigned int u32;
typedef __attribute__((ext_vector_type(8))) short s16x8;
typedef __attribute__((ext_vector_type(4))) short s16x4;
typedef __attribute__((ext_vector_type(4))) float f32x4;

#define S_LEN 4096
#define D_DIM 1024
#define NH    16
#define HDIM  64
#define KVB   128
#define QB    128

#define AS1 __attribute__((address_space(1)))
#define AS3 __attribute__((address_space(3)))

__device__ __forceinline__ u16 f2bf(float f) {
  unsigned u = __float_as_uint(f);
  u += 0x7FFF + ((u >> 16) & 1);   // RNE
  return (u16)(u >> 16);
}

// packed RNE f32x2 -> bf16x2 in one op
__device__ __forceinline__ u32 cvtpk2(float a, float b) {
  float r;
  asm("v_cvt_pk_bf16_f32 %0, %1, %2" : "=v"(r) : "v"(a), "v"(b));
  return __float_as_uint(r);
}

__device__ __forceinline__ u16 f2bf_pk(float f) {
  return (u16)(cvtpk2(f, f) & 0xffffu);
}

// 2^x in one instruction
__device__ __forceinline__ float exp2fast(float x) {
  float r;
  asm("v_exp_f32 %0, %1" : "=v"(r) : "v"(x));
  return r;
}

// async global->LDS, 16B per lane; LDS dest is wave-uniform (HW adds lane*16)
__device__ __forceinline__ void load_lds16(const void* g, void* l) {
  __builtin_amdgcn_global_load_lds((AS1 void*)g, (AS3 void*)l, 16, 0, 0);
}

__device__ __forceinline__ unsigned lds_addr32(const void* p) {
  return (unsigned)(unsigned long long)(AS3 const char*)p;
}

// hardware transpose read: on a row-major [16][16] bf16 subtile with per-lane
// addr = base + l*8, lane(g,r) receives elements [row=4g+j][col=r], j=0..3
__device__ __forceinline__ s16x4 ds_read_tr16(unsigned addr) {
  s16x4 r;
  asm volatile("ds_read_b64_tr_b16 %0, %1" : "=v"(r) : "v"(addr));
  return r;
}

// ---------------- fp32 -> bf16 (x in 4 slabs + 4 weights, one launch) --------
__global__ __launch_bounds__(256) void cvt_all(const float* __restrict__ x,
                                               const float* __restrict__ w0,
                                               const float* __restrict__ w1,
                                               const float* __restrict__ w2,
                                               const float* __restrict__ w3,
                                               u16* xb, u16* o0, u16* o1,
                                               u16* o2, u16* o3) {
  const float* in; u16* out;
  const int slab = blockIdx.y;
  switch (slab) {
    case 0: case 1: case 2: case 3:
      in = x + (size_t)slab * D_DIM * 1024; out = xb + (size_t)slab * D_DIM * 1024; break;
    case 4: in = w0; out = o0; break;
    case 5: in = w1; out = o1; break;
    case 6: in = w2; out = o2; break;
    default: in = w3; out = o3; break;
  }
  int i = (blockIdx.x * 256 + threadIdx.x) * 4;
  float4 v = *(const float4*)(in + i);
  ushort4 o;
  o.x = f2bf(v.x); o.y = f2bf(v.y); o.z = f2bf(v.z); o.w = f2bf(v.w);
  *(ushort4*)(out + i) = o;
}

// ---------------- GEMM: C[M,N] = cscale * A[M,K] * B[N,K]^T ----------------
// m97 structure: tile 128x128, BK=32, 4 waves (2x2), wave tile 64x64 (4x4 frags),
// 16 MFMA : 8 ds_read_b128 per K-step, double-buffered LDS + prefetch.
struct GemmSmem { u16 As[2][128 * 32]; u16 Bs[2][128 * 32]; };   // 32 KB

template <bool BF16_OUT>
__device__ __forceinline__ void gemm_tile(GemmSmem& sm, const u16* __restrict__ A,
                                          const u16* __restrict__ B,
                                          void* __restrict__ C, int m0, int n0,
                                          int N, int K, float cscale) {
  const int t = threadIdx.x;
  const int l = t & 63, g = l >> 4, r = l & 15;
  const int w = t >> 6, wr = w >> 1, wc = w & 1;
  f32x4 acc[4][4] = {};
  const int swz = (g ^ ((r >> 1) & 3)) << 3;   // read-side granule XOR

  auto stage = [&](int buf, int k0) {
#pragma unroll
    for (int i = 0; i < 2; ++i) {              // A,B: 512 granules of 16B each
      const int gi = i * 256 + t;
      const int row = gi >> 2, cg = gi & 3;
      const int sc = cg ^ ((row >> 1) & 3);
      load_lds16(A + (size_t)(m0 + row) * K + k0 + sc * 8,
                 (char*)sm.As[buf] + (i * 256 + (t & 192)) * 16);
      load_lds16(B + (size_t)(n0 + row) * K + k0 + sc * 8,
                 (char*)sm.Bs[buf] + (i * 256 + (t & 192)) * 16);
    }
  };

  stage(0, 0);
  __syncthreads();
  int cur = 0;
  for (int k0 = 0; k0 < K; k0 += 32) {
    if (k0 + 32 < K) stage(cur ^ 1, k0 + 32);
    s16x8 a[4], b[4];
#pragma unroll
    for (int m = 0; m < 4; ++m)
      a[m] = *(const s16x8*)&sm.As[cur][(wr * 64 + m * 16 + r) * 32 + swz];
#pragma unroll
    for (int n = 0; n < 4; ++n)
      b[n] = *(const s16x8*)&sm.Bs[cur][(wc * 64 + n * 16 + r) * 32 + swz];
#pragma unroll
    for (int m = 0; m < 4; ++m)
#pragma unroll
      for (int n = 0; n < 4; ++n)
        acc[m][n] = __builtin_amdgcn_mfma_f32_16x16x32_bf16(a[m], b[n], acc[m][n], 0, 0, 0);
    __syncthreads();
    cur ^= 1;
  }
  // D layout (verified): col = lane&15, row = 4*(lane>>4) + reg
#pragma unroll
  for (int m = 0; m < 4; ++m)
#pragma unroll
    for (int n = 0; n < 4; ++n)
#pragma unroll
      for (int v = 0; v < 4; ++v) {
        int row = m0 + wr * 64 + m * 16 + g * 4 + v;
        int col = n0 + wc * 64 + n * 16 + r;
        float val = acc[m][n][v] * cscale;
        if (BF16_OUT)
          ((u16*)C)[(size_t)row * N + col] = f2bf_pk(val);
        else
          ((float*)C)[(size_t)row * N + col] = val;
      }
}

// Q is pre-scaled by 0.125*log2(e) so attention works in exp2 domain
#define QSCALE 0.1803368801111204f

__global__ __launch_bounds__(256) void gemm_qkv(const u16* __restrict__ A,
                                                const u16* __restrict__ Bq,
                                                const u16* __restrict__ Bk,
                                                const u16* __restrict__ Bv,
                                                u16* Cq, u16* Ck, u16* Cv_) {
  __shared__ GemmSmem sm;
  // XCD chunk = 3 n-panels x all 32 m-rows: B slice (3x256KB) stays L2-resident,
  // A streams through L3. 768 = 8 XCD x 96; HW round-robins linear id % 8.
  const int f = blockIdx.y * 24 + blockIdx.x;
  const int c = f & 7, i = f >> 3;             // XCD, index within chunk (0..95)
  const int nbx = c * 3 + (i >> 5);            // 0..23
  const int nby = i & 31;                      // 0..31
  const int which = nbx >> 3;                  // 8 n-blocks of 128 per matrix
  const u16* B = which == 0 ? Bq : (which == 1 ? Bk : Bv);
  u16* C = which == 0 ? Cq : (which == 1 ? Ck : Cv_);
  const float cs = which == 0 ? QSCALE : 1.0f;
  gemm_tile<true>(sm, A, B, C, nby * 128, (nbx & 7) * 128, D_DIM, D_DIM, cs);
}

__global__ __launch_bounds__(256) void gemm_out(const u16* __restrict__ A,
                                                const u16* __restrict__ B,
                                                float* __restrict__ C) {
  __shared__ GemmSmem sm;
  // XCD chunk = 1 n-panel x 32 m-rows: B panel (256KB) L2-resident.
  const int f = blockIdx.y * 8 + blockIdx.x;
  const int c = f & 7, i = f >> 3;
  gemm_tile<false>(sm, A, B, C, i * 128, c * 128, D_DIM, D_DIM, 1.0f);
}

// ---------------- causal flash attention (swapped operands, R6 struct) -------
// QBLK=128, 8 waves (512 thr), 16 q-rows/wave; diagonal-paired: block x does
// q-tile (31-x) then q-tile x -> exactly 33 KV-128 tiles/block; 256 blocks
// (1/CU).
__global__ __launch_bounds__(512) void flash_attn(const u16* __restrict__ Q,
                                                  const u16* __restrict__ Kg,
                                                  const u16* __restrict__ V,
                                                  u16* __restrict__ CTX) {
  const int h = blockIdx.y;
  const int hoff = h * HDIM;
  const int t = threadIdx.x, w = t >> 6, l = t & 63, g = l >> 4, r = l & 15;

  __shared__ u16 Kt[2][KVB * 64];    // [kv][hd], granule-XOR swizzled (row&7)
  __shared__ u16 Vt[2][32 * 256];    // 32 subtiles [16kv][16hd] for tr-reads

  auto stage = [&](int buf, int kv0) {
#pragma unroll
    for (int i = 0; i < 2; ++i) {    // 1024 granules each of K and V, 512 thr
      const int gi = i * 512 + t;
      const int krow = gi >> 3, c0 = gi & 7;
      load_lds16(Kg + (size_t)(kv0 + krow) * D_DIM + hoff + ((c0 ^ (krow & 7)) << 3),
                 (char*)Kt[buf] + (i * 512 + (t & 448)) * 16);
      const int sv = gi >> 5, vo = gi & 31;
      load_lds16(V + (size_t)(kv0 + (sv >> 2) * 16 + (vo >> 1)) * D_DIM + hoff +
                     (sv & 3) * 16 + (vo & 1) * 8,
                 (char*)Vt[buf] + (i * 512 + (t & 448)) * 16);
    }
  };

#pragma unroll 1
  for (int run = 0; run < 2; ++run) {
    const int qt = run == 0 ? (31 - (int)blockIdx.x) : (int)blockIdx.x;
    const int q0 = qt * QB + w * 16;
    const int nt = qt + 1;

    // Q fragments (B-operand of swapped QK): row = q0+r, k = hd contiguous-8
    const u16* qrow = Q + (size_t)(q0 + r) * D_DIM + hoff;
    const s16x8 aq0 = *(const s16x8*)(qrow + g * 8);
    const s16x8 aq1 = *(const s16x8*)(qrow + 32 + g * 8);

    f32x4 o[4] = {};                 // O^T: hd = 16*hb + 4g+reg, q = r
    float mrun = -1e30f, lsum = 0.f;

    stage(0, 0);
    __syncthreads();
    int cur = 0;

    for (int tile = 0; tile < nt; ++tile) {
      if (tile + 1 < nt) stage(cur ^ 1, (tile + 1) * KVB);
      const u16* Kb = Kt[cur];
      const bool lastT = (tile == nt - 1);

      // ---- S^T[128kv x 16q] = K·Q^T: s[nb][j] -> kv = 16nb+4g+j, q = r ----
      f32x4 s[8];
      __builtin_amdgcn_s_setprio(1);
#pragma unroll
      for (int nb = 0; nb < 8; ++nb) {
        const int kr = nb * 16 + r;
        const int sw = kr & 7;
        s16x8 bk0 = *(const s16x8*)&Kb[kr * 64 + ((g ^ sw) << 3)];
        s16x8 bk1 = *(const s16x8*)&Kb[kr * 64 + (((4 + g) ^ sw) << 3)];
        f32x4 z = {0.f, 0.f, 0.f, 0.f};
        z = __builtin_amdgcn_mfma_f32_16x16x32_bf16(bk0, aq0, z, 0, 0, 0);
        z = __builtin_amdgcn_mfma_f32_16x16x32_bf16(bk1, aq1, z, 0, 0, 0);
        s[nb] = z;
      }
      __builtin_amdgcn_s_setprio(0);

      // ---- causal mask (diagonal tile only); per-lane q threshold ----
      if (lastT) {
        const int qrel = q0 + r - tile * KVB;
#pragma unroll
        for (int nb = 0; nb < 8; ++nb)
#pragma unroll
          for (int j = 0; j < 4; ++j)
            if (16 * nb + 4 * g + j > qrel) s[nb][j] = -1e30f;
      }

      // ---- online softmax: in-lane over 32, then xor16+xor32 across g ----
      float tm = -1e30f;
#pragma unroll
      for (int nb = 0; nb < 8; ++nb) {
        float a0 = fmaxf(s[nb][0], s[nb][1]), a1 = fmaxf(s[nb][2], s[nb][3]);
        tm = fmaxf(tm, fmaxf(a0, a1));
      }
      tm = fmaxf(tm, __shfl_xor(tm, 16, 64));
      tm = fmaxf(tm, __shfl_xor(tm, 32, 64));
      const float mnew = fmaxf(mrun, tm);
      const float fs = exp2fast(mrun - mnew);
      mrun = mnew;
      float ps = 0.f;
#pragma unroll
      for (int nb = 0; nb < 8; ++nb)
#pragma unroll
        for (int j = 0; j < 4; ++j) {
          const float pv = exp2fast(s[nb][j] - mnew);
          s[nb][j] = pv;
          ps += pv;
        }
      ps += __shfl_xor(ps, 16, 64);
      ps += __shfl_xor(ps, 32, 64);
      lsum = lsum * fs + ps;
#pragma unroll
      for (int hb = 0; hb < 4; ++hb) {
        o[hb][0] *= fs; o[hb][1] *= fs; o[hb][2] *= fs; o[hb][3] *= fs;
      }

      // ---- pack P^T fragments: lane's own values ARE the B-operand ----
      // k-map (both sides): k = 4g + (e&3) + 16*(e>>2), kv = 32ks + k
      s16x8 pa[4];
#pragma unroll
      for (int ks = 0; ks < 4; ++ks) {
        union { u32 u[4]; s16x8 v; } pk_;
        pk_.u[0] = cvtpk2(s[2 * ks][0],     s[2 * ks][1]);
        pk_.u[1] = cvtpk2(s[2 * ks][2],     s[2 * ks][3]);
        pk_.u[2] = cvtpk2(s[2 * ks + 1][0], s[2 * ks + 1][1]);
        pk_.u[3] = cvtpk2(s[2 * ks + 1][2], s[2 * ks + 1][3]);
        pa[ks] = pk_.v;
      }

      // ---- PV swapped: o[hb] += V^T_frag[ks][hb] · pa[ks] ----
      // tr-reads in 8-read groups, 2 groups in flight, counted waits <=15
      const unsigned vbase = lds_addr32(Vt[cur]) + (unsigned)(l * 8);
      s16x4 tv[4][4][2];             // [ks][hb][half]
      auto issue_grp = [&](int ks) {
#pragma unroll
        for (int hb = 0; hb < 4; ++hb) {
          tv[ks][hb][0] = ds_read_tr16(vbase + (unsigned)(((2 * ks) * 4 + hb) * 512));
          tv[ks][hb][1] = ds_read_tr16(vbase + (unsigned)(((2 * ks + 1) * 4 + hb) * 512));
        }
      };
      issue_grp(0);
      issue_grp(1);
#pragma unroll
      for (int ks = 0; ks < 4; ++ks) {
        if (ks < 3) asm volatile("s_waitcnt lgkmcnt(8)" ::: "memory");
        else        asm volatile("s_waitcnt lgkmcnt(0)" ::: "memory");
        __builtin_amdgcn_sched_barrier(0);
        __builtin_amdgcn_s_setprio(1);
#pragma unroll
        for (int hb = 0; hb < 4; ++hb) {
          s16x8 vf = {tv[ks][hb][0][0], tv[ks][hb][0][1], tv[ks][hb][0][2], tv[ks][hb][0][3],
                      tv[ks][hb][1][0], tv[ks][hb][1][1], tv[ks][hb][1][2], tv[ks][hb][1][3]};
          o[hb] = __builtin_amdgcn_mfma_f32_16x16x32_bf16(vf, pa[ks], o[hb], 0, 0, 0);
        }
        __builtin_amdgcn_s_setprio(0);
        if (ks < 2) issue_grp(ks + 2);       // overlap next group with this MFMA
      }
      __syncthreads();               // prefetch landed; all reads of cur done
      cur ^= 1;
    }

    // ---- normalize + store O^T: lane(g,r): q = q0+r, hd = 16hb+4g+0..3 ----
    const float inv = 1.0f / lsum;
    u16* crow = CTX + (size_t)(q0 + r) * D_DIM + hoff + 4 * g;
#pragma unroll
    for (int hb = 0; hb < 4; ++hb) {
      uint2 pk_;
      pk_.x = cvtpk2(o[hb][0] * inv, o[hb][1] * inv);
      pk_.y = cvtpk2(o[hb][2] * inv, o[hb][3] * inv);
      *(uint2*)(crow + hb * 16) = pk_;
    }
  }
}

extern "C" void kernel_launch(void* const* d_in, const int* in_sizes, int n_in,
                              void* d_out, int out_size, void* d_ws, size_t ws_size,
                              hipStream_t stream) {
  const float* x  = (const float*)d_in[0];
  const float* Wq = (const float*)d_in[1];
  const float* Wk = (const float*)d_in[2];
  const float* Wv = (const float*)d_in[3];
  const float* Wo = (const float*)d_in[4];

  u16* xb  = (u16*)d_ws;                               // 4096x1024
  u16* Wqb = xb + (size_t)S_LEN * D_DIM;               // 1024x1024 each
  u16* Wkb = Wqb + (size_t)D_DIM * D_DIM;
  u16* Wvb = Wkb + (size_t)D_DIM * D_DIM;
  u16* Wob = Wvb + (size_t)D_DIM * D_DIM;
  u16* Qb  = Wob + (size_t)D_DIM * D_DIM;              // 4096x1024 each
  u16* Kb  = Qb + (size_t)S_LEN * D_DIM;
  u16* Vb  = Kb + (size_t)S_LEN * D_DIM;
  u16* Cb  = Vb + (size_t)S_LEN * D_DIM;

  cvt_all<<<dim3(1024, 8), 256, 0, stream>>>(x, Wq, Wk, Wv, Wo,
                                             xb, Wqb, Wkb, Wvb, Wob);
  gemm_qkv<<<dim3(24, 32), 256, 0, stream>>>(xb, Wqb, Wkb, Wvb, Qb, Kb, Vb);
  flash_attn<<<dim3(S_LEN / QB / 2, NH), 512, 0, stream>>>(Qb, Kb, Vb, Cb);
  gemm_out<<<dim3(8, 32), 256, 0, stream>>>(Cb, Wob, (float*)d_out);
}